// Round 7
// baseline (164.872 us; speedup 1.0000x reference)
//
#include <hip/hip_runtime.h>

#define R_ 3
#define D_ 7            // 2R+1
#define W_ 49
#define N_ 128
#define K_ 131
#define C_ 21
#define B_ 2
#define NN (N_ * N_)
#define TI_ 8                   // tile rows
#define TJ_ 16                  // tile cols
#define PROWS (TI_ + 2 * R_)    // 14
#define PCOLS (TJ_ + 2 * R_)    // 22
#define PSTR 24                 // LDS row stride (float2 pairs)
#define NELEM (PROWS * PCOLS)   // 308 staged elements
#define LDSP ((PROWS + 1) * PSTR)      // 360 pairs: extra zero row 14 for h=3 dummy taps
#define KC 4                    // k-chunks per tile
#define KCHUNK ((K_ + KC - 1) / KC)    // 33

// Affinity: per-pixel 7x7 window softmax per channel, weighted by cp[k].
// exp(|c-n|) = max(Ec*EnInv, En*EcInv), (E,Einv) staged once per element.
// 4 threads per pixel: h=tid&3 owns window rows u=h and u=h+4 (h<3).
// h=3's second row reads the dedicated zero row 14 (ti-independent!) -> taps=0.
// Row taps are 7 consecutive pairs -> ds_read2_b64 merging.
// Aout layout: [B][W][NN], atomically accumulated across KC k-chunks.
__global__ __launch_bounds__(512, 4) void rwn_affinity(
    const float* __restrict__ feats,   // [B,K,N,N]
    const int*   __restrict__ mask,    // [B,N,N]
    const float* __restrict__ cp,      // [K]
    float* __restrict__ Aout)          // [B,W,NN] (pre-zeroed)
{
    __shared__ float2 patch2[LDSP];

    const int tile = blockIdx.x;           // 0..127 (16 x 8 tiles of 8x16)
    const int kc   = blockIdx.y;
    const int b    = blockIdx.z;
    const int tr = tile >> 3, tc = tile & 7;
    const int ti0 = tr * TI_, tj0 = tc * TJ_;

    const int tid = threadIdx.x;
    const int pix = tid >> 2;              // 0..127
    const int h   = tid & 3;               // row-group owner
    const int ti = pix >> 4;               // 0..7
    const int tj = pix & 15;               // 0..15
    const int gi = ti0 + ti, gj = tj0 + tj;

    // ---- staging setup: thread owns element tid (<308) ----
    const bool act = (tid < NELEM);
    int pr = tid / PCOLS, pc = tid - pr * PCOLS;
    int mi = ti0 + pr - R_, mj = tj0 + pc - R_;
    const bool inb = act && mi >= 0 && mi < N_ && mj >= 0 && mj < N_;
    int cmi = mi < 0 ? 0 : (mi > N_ - 1 ? N_ - 1 : mi);
    int cmj = mj < 0 ? 0 : (mj > N_ - 1 ? N_ - 1 : mj);
    const int   soff = inb ? (cmi * N_ + cmj) : 0;
    const float swt  = inb ? (float)mask[b * NN + soff] : 0.f;
    const float ozw  = inb ? 1.f : 0.f;
    const int   slds = pr * PSTR + pc;

    const int cbase = ti * PSTR + tj;      // pair addr of (pixel - (3,3))
    const int ub0 = cbase + h * PSTR;      // row u=h (patch row ti+h)
    // row u=h+4 for h<3 (patch row ti+h+4); h=3 -> ALWAYS the zero row 14
    const int ub1 = (h < 3) ? (cbase + (h + 4) * PSTR) : (PROWS * PSTR + tj);

    float Aacc[14];
    #pragma unroll
    for (int i = 0; i < 14; ++i) Aacc[i] = 0.f;

    const int k0 = kc * KCHUNK;
    const int k1 = (k0 + KCHUNK < K_) ? (k0 + KCHUNK) : K_;
    const float* fb = feats + (size_t)b * K_ * NN;

    // zero row 14 once (never re-written; h=3 dummy taps read it)
    for (int e = tid; e < PSTR; e += 512)
        patch2[PROWS * PSTR + e] = make_float2(0.f, 0.f);

    // software prefetch of first k (already mask-weighted)
    float pre = fb[(size_t)k0 * NN + soff] * swt;

    __syncthreads();

    for (int k = k0; k < k1; ++k) {
        if (act)
            patch2[slds] = make_float2(ozw * __expf(pre), ozw * __expf(-pre));
        // prefetch next k while this one computes
        float nx = 0.f;
        if (k + 1 < k1)
            nx = fb[(size_t)(k + 1) * NN + soff] * swt;
        __syncthreads();

        const float2 cpair = patch2[cbase + R_ * PSTR + R_];
        float ex[14];
        float dsum = 0.f;
        #pragma unroll
        for (int v = 0; v < D_; ++v) {
            const float2 np = patch2[ub0 + v];
            float t = fmaxf(cpair.x * np.y, np.x * cpair.y); // exp(|c-n|)
            ex[v] = t;
            dsum += t;
        }
        #pragma unroll
        for (int v = 0; v < D_; ++v) {
            const float2 np = patch2[ub1 + v];               // h=3: zero row
            float t = fmaxf(cpair.x * np.y, np.x * cpair.y);
            ex[7 + v] = t;
            dsum += t;
        }
        // reduce denom across the 4 lanes of this pixel
        dsum += __shfl_xor(dsum, 1, 64);
        dsum += __shfl_xor(dsum, 2, 64);
        const float scale = cp[k] * __frcp_rn(dsum);         // denom >= 1
        #pragma unroll
        for (int idx = 0; idx < 14; ++idx) Aacc[idx] += scale * ex[idx];
        __syncthreads();

        pre = nx;
    }

    if (mask[b * NN + gi * N_ + gj] != 0) {
        const int pixg = gi * N_ + gj;
        float* ab = Aout + (size_t)b * W_ * NN + pixg;
        #pragma unroll
        for (int v = 0; v < D_; ++v)
            atomicAdd(ab + (h * D_ + v) * NN, Aacc[v]);
        if (h < 3) {
            #pragma unroll
            for (int v = 0; v < D_; ++v)
                atomicAdd(ab + ((h + 4) * D_ + v) * NN, Aacc[7 + v]);
        }
    }
}

// Gather: out[b,q,c] = sum_w A[b,w,p]*x2[b,c,p], p=q-(u-3,v-3), w=u*7+v.
// Block = 64 q x 8 w-groups (512 thr); wg owns u=wg (wg=7 idle in taps).
// 21 c-accumulators in registers; LDS reduce over 8 planes; contiguous store.
#define RSTR 22   // LDS reduce stride
__global__ __launch_bounds__(512, 4) void rwn_gather(
    const float* __restrict__ Aarr,  // [B,W,NN]
    const float* __restrict__ x2,    // [B,C,NN]
    float* __restrict__ out)         // [B,NN,C]
{
    __shared__ float red[8 * 64 * RSTR];   // 45056 B

    const int q0 = blockIdx.x * 64;
    const int b  = blockIdx.y;
    const int tid = threadIdx.x;
    const int qh = tid & 63;         // lane -> consecutive q (coalesced)
    const int wg = tid >> 6;         // wave-uniform w-group = u
    const int q = q0 + qh;
    const int i = q >> 7, j = q & (N_ - 1);

    const float* Ab = Aarr + (size_t)b * W_ * NN;
    const float* xb = x2 + (size_t)b * C_ * NN;

    float acc[C_];
    #pragma unroll
    for (int c = 0; c < C_; ++c) acc[c] = 0.f;

    if (wg < D_) {
        const int pi = i - (wg - R_);
        const int cpi = pi < 0 ? 0 : (pi > N_ - 1 ? N_ - 1 : pi);
        const float rv = (pi >= 0 && pi < N_) ? 1.f : 0.f;
        const float* Aw = Ab + (size_t)wg * D_ * NN;
        #pragma unroll
        for (int v = 0; v < D_; ++v) {
            const int pj = j - (v - R_);
            const int cpj = pj < 0 ? 0 : (pj > N_ - 1 ? N_ - 1 : pj);
            const float vv = (pj >= 0 && pj < N_) ? rv : 0.f;
            const int p = cpi * N_ + cpj;
            const float a = vv * Aw[(size_t)v * NN + p];
            #pragma unroll
            for (int c = 0; c < C_; ++c)
                acc[c] += a * xb[(size_t)c * NN + p];
        }
    }

    // stage per-wg partials
    float* rbase = red + (wg * 64 + qh) * RSTR;
    #pragma unroll
    for (int c = 0; c < C_; ++c) rbase[c] = acc[c];
    __syncthreads();

    // reduce 8 planes, store contiguous (64*21 = 1344 floats)
    float* ob = out + ((size_t)b * NN + q0) * C_;
    for (int e = tid; e < 64 * C_; e += 512) {
        const int qq = e / C_, cc = e - qq * C_;
        const int a = qq * RSTR + cc;
        float s = 0.f;
        #pragma unroll
        for (int pl = 0; pl < 8; ++pl)
            s += red[pl * 64 * RSTR + a];
        ob[e] = s;
    }
}

extern "C" void kernel_launch(void* const* d_in, const int* in_sizes, int n_in,
                              void* d_out, int out_size, void* d_ws, size_t ws_size,
                              hipStream_t stream) {
    const float* feats = (const float*)d_in[0];   // [B,K,N,N]
    const float* x2    = (const float*)d_in[1];   // [B,C,NN]
    const int*   mask  = (const int*)d_in[2];     // [B,N,N]
    const float* cp    = (const float*)d_in[3];   // [K]
    float* out = (float*)d_out;

    float* Aarr = (float*)d_ws;                   // [B,W,NN] fp32
    const size_t Abytes = (size_t)B_ * W_ * NN * sizeof(float);

    hipMemsetAsync(Aarr, 0, Abytes, stream);

    dim3 gridA(128, KC, B_);
    rwn_affinity<<<gridA, 512, 0, stream>>>(feats, mask, cp, Aarr);

    dim3 gridG(NN / 64, B_);
    rwn_gather<<<gridG, 512, 0, stream>>>(Aarr, x2, out);
}

// Round 10
// 149.879 us; speedup vs baseline: 1.1000x; 1.1000x over previous
//
#include <hip/hip_runtime.h>
#include <hip/hip_fp16.h>

#define R_ 3
#define D_ 7            // 2R+1
#define W_ 49
#define N_ 128
#define K_ 131
#define C_ 21
#define B_ 2
#define NN (N_ * N_)
#define TI_ 8                   // tile rows
#define TJ_ 16                  // tile cols
#define PROWS (TI_ + 2 * R_)    // 14
#define PCOLS (TJ_ + 2 * R_)    // 22
#define PSTR 24                 // LDS row stride (float2 pairs)
#define NELEM (PROWS * PCOLS)   // 308 staged elements
#define LDSP (PROWS * PSTR + 8) // 344 pairs (spare write slot at 340)
#define KC 8                    // k-chunks per tile
#define KCHUNK ((K_ + KC - 1) / KC)    // 17

typedef __fp16 h2 __attribute__((ext_vector_type(2)));

// Affinity: per-pixel 7x7 window softmax per channel, weighted by cp[k].
// exp(|c-n|) = max(Ec*EnInv, En*EcInv), (E,Einv) pairs staged per element
// (E = exp2(f*mask*log2e)). Lane pairs (2t,2t+1) share a pixel; h=tid&1 owns
// columns v=2s+h (s=0..3). The h=1,s=3 slot is the phantom v=7 tap: it reads
// a REAL staged element (column tj+7) for tj<15, so it MUST be killed
// explicitly with ph (lesson of R9's absmax=7 failure).
// ex/Aacc kept as PACKED f16 (14 half2 each) -> no AGPR spill; accumulation
// via v_pk_fma_f16. Aout [B][W][NN], atomic-accumulated across KC k-chunks.
__global__ __launch_bounds__(256) void rwn_affinity(
    const float* __restrict__ feats,   // [B,K,N,N]
    const int*   __restrict__ mask,    // [B,N,N]
    const float* __restrict__ cp,      // [K]
    float* __restrict__ Aout)          // [B,W,NN] (pre-zeroed)
{
    __shared__ float2 patch2[LDSP];

    const int tile = blockIdx.x;           // 0..127 (16x8 tiles of 8x16)
    const int kc   = blockIdx.y;
    const int b    = blockIdx.z;
    const int tr = tile >> 3, tc = tile & 7;
    const int ti0 = tr * TI_, tj0 = tc * TJ_;

    const int tid = threadIdx.x;
    const int pix = tid >> 1;              // 0..127
    const int h   = tid & 1;               // column-parity owner
    const int ti = pix >> 4;               // 0..7
    const int tj = pix & 15;               // 0..15
    const int gi = ti0 + ti, gj = tj0 + tj;

    // ---- hoisted staging setup: thread owns elements tid and 256+tid ----
    const float LOG2E = 1.4426950408889634f;
    int   soff[2];      // clamped global offset
    float swt[2];       // in-bounds * mask * log2e
    float ozw[2];       // 0 for OOB (store zero pair), 1 otherwise
    int   slds[2];      // pair index in LDS
    #pragma unroll
    for (int r = 0; r < 2; ++r) {
        int e = tid + r * 256;
        bool act = (e < NELEM);
        int pr = e / PCOLS, pc = e - pr * PCOLS;
        int mi = ti0 + pr - R_, mj = tj0 + pc - R_;
        bool inb = act && mi >= 0 && mi < N_ && mj >= 0 && mj < N_;
        int cmi = mi < 0 ? 0 : (mi > N_ - 1 ? N_ - 1 : mi);
        int cmj = mj < 0 ? 0 : (mj > N_ - 1 ? N_ - 1 : mj);
        soff[r] = cmi * N_ + cmj;
        swt[r]  = inb ? ((float)mask[b * NN + soff[r]] * LOG2E) : 0.f;
        ozw[r]  = inb ? 1.f : 0.f;
        slds[r] = act ? (pr * PSTR + pc) : (PROWS * PSTR + 4);  // spare slot
    }

    const float ph = h ? 0.f : 1.f;        // phantom v=7 killer (h=1,s=3)
    const int cbase = ti * PSTR + tj;      // pair addr of (pixel - (3,3))
    const int bh = cbase + h;              // single base for all 28 taps

    h2 Aacc[14];
    #pragma unroll
    for (int i = 0; i < 14; ++i) Aacc[i] = (h2){(__fp16)0.f, (__fp16)0.f};

    const int k0 = kc * KCHUNK;
    const int k1 = (k0 + KCHUNK < K_) ? (k0 + KCHUNK) : K_;
    const float* fb = feats + (size_t)b * K_ * NN;

    // zero-init all LDS pairs once: pad cols 22,23 / spare slot stay 0 forever
    for (int e = tid; e < LDSP; e += 256) patch2[e] = make_float2(0.f, 0.f);

    // software prefetch of first k (pre = f * mask * log2e)
    const float* fk0 = fb + (size_t)k0 * NN;
    float pre0 = fk0[soff[0]] * swt[0];
    float pre1 = fk0[soff[1]] * swt[1];

    __syncthreads();

    for (int k = k0; k < k1; ++k) {
        patch2[slds[0]] = make_float2(ozw[0] * exp2f(pre0), ozw[0] * exp2f(-pre0));
        patch2[slds[1]] = make_float2(ozw[1] * exp2f(pre1), ozw[1] * exp2f(-pre1));
        // prefetch next k while this one computes
        float n0 = 0.f, n1 = 0.f;
        if (k + 1 < k1) {
            const float* fn = fb + (size_t)(k + 1) * NN;
            n0 = fn[soff[0]] * swt[0];
            n1 = fn[soff[1]] * swt[1];
        }
        __syncthreads();

        const float2 cpair = patch2[cbase + R_ * PSTR + R_];
        h2 ex[14];
        float dsum = 0.f;
        #pragma unroll
        for (int u = 0; u < D_; ++u) {
            #pragma unroll
            for (int m = 0; m < 2; ++m) {
                // taps s=2m (t0) and s=2m+1 (t1); pair offsets 4m, 4m+2
                const float2 np0 = patch2[bh + u * PSTR + 4 * m];
                const float2 np1 = patch2[bh + u * PSTR + 4 * m + 2];
                float t0 = fmaxf(cpair.x * np0.y, np0.x * cpair.y);
                float t1 = fmaxf(cpair.x * np1.y, np1.x * cpair.y);
                if (m == 1) t1 *= ph;   // kill phantom v=7 (reads REAL data!)
                dsum += t0;
                dsum += t1;
                ex[u * 2 + m] = __builtin_amdgcn_cvt_pkrtz(t0, t1);
            }
        }
        const float denom = dsum + __shfl_xor(dsum, 1, 64);  // lane pair = pixel
        const float scale = cp[k] * __frcp_rn(denom);        // denom >= 1
        const h2 s2 = __builtin_amdgcn_cvt_pkrtz(scale, scale);
        #pragma unroll
        for (int m = 0; m < 14; ++m) Aacc[m] = ex[m] * s2 + Aacc[m];
        __syncthreads();

        pre0 = n0; pre1 = n1;
    }

    if (mask[b * NN + gi * N_ + gj] != 0) {
        const int pixg = gi * N_ + gj;
        // w = u*7 + 2s + h; s=2m -> offset 4m; s=2m+1 -> offset 4m+2
        float* ab = Aout + (size_t)b * W_ * NN + h * NN + pixg;
        #pragma unroll
        for (int u = 0; u < D_; ++u) {
            #pragma unroll
            for (int m = 0; m < 2; ++m) {
                const h2 tv = Aacc[u * 2 + m];
                atomicAdd(ab + (u * D_ + 4 * m) * NN, (float)tv[0]);
                if (h == 0 || m < 1)   // h=1,m=1 second tap = phantom v=7
                    atomicAdd(ab + (u * D_ + 4 * m + 2) * NN, (float)tv[1]);
            }
        }
    }
}

// Gather: out[b,q,c] = sum_w A[b,w,p]*x2[b,c,p], p=q-(u-3,v-3), w=u*7+v.
// Block = 64 q x 8 w-groups (512 thr); wg owns u=wg (wg=7 idle in taps).
// 21 c-accumulators in registers; LDS reduce over 8 planes; contiguous store.
#define RSTR 22   // LDS reduce stride
__global__ __launch_bounds__(512, 4) void rwn_gather(
    const float* __restrict__ Aarr,  // [B,W,NN]
    const float* __restrict__ x2,    // [B,C,NN]
    float* __restrict__ out)         // [B,NN,C]
{
    __shared__ float red[8 * 64 * RSTR];   // 45056 B

    const int q0 = blockIdx.x * 64;
    const int b  = blockIdx.y;
    const int tid = threadIdx.x;
    const int qh = tid & 63;         // lane -> consecutive q (coalesced)
    const int wg = tid >> 6;         // wave-uniform w-group = u
    const int q = q0 + qh;
    const int i = q >> 7, j = q & (N_ - 1);

    const float* Ab = Aarr + (size_t)b * W_ * NN;
    const float* xb = x2 + (size_t)b * C_ * NN;

    float acc[C_];
    #pragma unroll
    for (int c = 0; c < C_; ++c) acc[c] = 0.f;

    if (wg < D_) {
        const int pi = i - (wg - R_);
        const int cpi = pi < 0 ? 0 : (pi > N_ - 1 ? N_ - 1 : pi);
        const float rv = (pi >= 0 && pi < N_) ? 1.f : 0.f;
        const float* Aw = Ab + (size_t)wg * D_ * NN;
        #pragma unroll
        for (int v = 0; v < D_; ++v) {
            const int pj = j - (v - R_);
            const int cpj = pj < 0 ? 0 : (pj > N_ - 1 ? N_ - 1 : pj);
            const float vv = (pj >= 0 && pj < N_) ? rv : 0.f;
            const int p = cpi * N_ + cpj;
            const float a = vv * Aw[(size_t)v * NN + p];
            #pragma unroll
            for (int c = 0; c < C_; ++c)
                acc[c] += a * xb[(size_t)c * NN + p];
        }
    }

    // stage per-wg partials
    float* rbase = red + (wg * 64 + qh) * RSTR;
    #pragma unroll
    for (int c = 0; c < C_; ++c) rbase[c] = acc[c];
    __syncthreads();

    // reduce 8 planes, store contiguous (64*21 = 1344 floats)
    float* ob = out + ((size_t)b * NN + q0) * C_;
    for (int e = tid; e < 64 * C_; e += 512) {
        const int qq = e / C_, cc = e - qq * C_;
        const int a = qq * RSTR + cc;
        float s = 0.f;
        #pragma unroll
        for (int pl = 0; pl < 8; ++pl)
            s += red[pl * 64 * RSTR + a];
        ob[e] = s;
    }
}

extern "C" void kernel_launch(void* const* d_in, const int* in_sizes, int n_in,
                              void* d_out, int out_size, void* d_ws, size_t ws_size,
                              hipStream_t stream) {
    const float* feats = (const float*)d_in[0];   // [B,K,N,N]
    const float* x2    = (const float*)d_in[1];   // [B,C,NN]
    const int*   mask  = (const int*)d_in[2];     // [B,N,N]
    const float* cp    = (const float*)d_in[3];   // [K]
    float* out = (float*)d_out;

    float* Aarr = (float*)d_ws;                   // [B,W,NN] fp32
    const size_t Abytes = (size_t)B_ * W_ * NN * sizeof(float);

    (void)hipMemsetAsync(Aarr, 0, Abytes, stream);

    dim3 gridA(128, KC, B_);
    rwn_affinity<<<gridA, 256, 0, stream>>>(feats, mask, cp, Aarr);

    dim3 gridG(NN / 64, B_);
    rwn_gather<<<gridG, 512, 0, stream>>>(Aarr, x2, out);
}